// Round 4
// baseline (471.975 us; speedup 1.0000x reference)
//
#include <hip/hip_runtime.h>

typedef short bf16x8 __attribute__((ext_vector_type(8)));
typedef float f32x4 __attribute__((ext_vector_type(4)));

// Problem constants (fixed by reference setup_inputs)
constexpr int Bc = 4;
constexpr int Nc = 50000;
constexpr int Kc = 10;
constexpr int Fc = 128;
constexpr int Hc = 16;
constexpr int Cc = 64;            // 4*H output channels
constexpr int NODES = Bc * Nc;    // 200000
constexpr int NPB = 8;            // nodes per block
constexpr int ROWS = NPB * Kc;    // 80 GEMM rows per block
constexpr int MT = ROWS / 16;     // 5 M-tiles
constexpr int BLK = 256;          // 4 waves (N-split: wave w owns cols 16w..16w+15)

__device__ __forceinline__ unsigned short f2bf(float f) {
    // round-to-nearest-even fp32 -> bf16
    unsigned u = __builtin_bit_cast(unsigned, f);
    return (unsigned short)((u + 0x7fffu + ((u >> 16) & 1u)) >> 16);
}

__device__ __forceinline__ bf16x8 cvt8(float4 a, float4 b) {
    bf16x8 r;
    r[0] = (short)f2bf(a.x); r[1] = (short)f2bf(a.y);
    r[2] = (short)f2bf(a.z); r[3] = (short)f2bf(a.w);
    r[4] = (short)f2bf(b.x); r[5] = (short)f2bf(b.y);
    r[6] = (short)f2bf(b.z); r[7] = (short)f2bf(b.w);
    return r;
}

// Prep: W [128][64] f32 -> per-lane B-fragment image in d_ws (bf16).
// dst element index = w*2048 + l*32 + kc*8 + j  maps to
//   c = w*16 + (l&15),  f = kc*32 + (l>>4)*8 + j,  value = bf16(W[f*64 + c]).
// So in the main kernel, thread (w,l) reads its 4 bfrags as 64 contiguous bytes.
__global__ __launch_bounds__(256)
void prep_w(const float* __restrict__ W, unsigned short* __restrict__ wt) {
    const int dst = blockIdx.x * 256 + threadIdx.x;   // 8192 total
    const int j  = dst & 7;
    const int kc = (dst >> 3) & 3;
    const int l  = (dst >> 5) & 63;
    const int w  = dst >> 11;
    const int c  = w * 16 + (l & 15);
    const int f  = kc * 32 + (l >> 4) * 8 + j;
    wt[dst] = f2bf(W[f * 64 + c]);
}

__global__ __launch_bounds__(BLK, 4)
void gat_kernel(const float* __restrict__ x,
                const unsigned short* __restrict__ wt_ws,
                const float* __restrict__ a,
                float* __restrict__ out)
{
    __shared__ float hw[ROWS * 68];   // 21760 B
    __shared__ float ol[NPB * 68];    //  2176 B

    const int t  = threadIdx.x;
    const int w  = t >> 6;    // wave -> col-tile
    const int l  = t & 63;
    const int lr = l & 15;    // A-row / B-col within tile
    const int lk = l >> 4;    // k sub-block (8 contiguous k)

    // B fragments: 64 contiguous bytes per lane from the prepped image (L1/L2-hit)
    bf16x8 bfrag[4];
    {
        const bf16x8* wp = reinterpret_cast<const bf16x8*>(wt_ws + w * 2048 + l * 32);
#pragma unroll
        for (int kc = 0; kc < 4; ++kc) bfrag[kc] = wp[kc];
    }

    // ---- GEMM: direct-from-global A-frags, no barrier on the hot path ----
    f32x4 acc[MT];
#pragma unroll
    for (int m = 0; m < MT; ++m) acc[m] = (f32x4){0.f, 0.f, 0.f, 0.f};

    const float* xb = x + ((size_t)blockIdx.x * ROWS + lr) * Fc + lk * 8;
#pragma unroll
    for (int m = 0; m < MT; ++m) {
        const float* ap = xb + (size_t)m * 16 * Fc;
        float4 u[4], v[4];
#pragma unroll
        for (int kc = 0; kc < 4; ++kc) {
            u[kc] = *reinterpret_cast<const float4*>(ap + kc * 32);
            v[kc] = *reinterpret_cast<const float4*>(ap + kc * 32 + 4);
        }
#pragma unroll
        for (int kc = 0; kc < 4; ++kc)
            acc[m] = __builtin_amdgcn_mfma_f32_16x16x32_bf16(cvt8(u[kc], v[kc]), bfrag[kc], acc[m], 0, 0, 0);
    }

    // ---- acc -> hw LDS [80][68] (D-frag: row = lk*4+r, col = lr) ----
    {
        const int col = w * 16 + lr;
#pragma unroll
        for (int m = 0; m < MT; ++m) {
            const int rbase = m * 16 + lk * 4;
#pragma unroll
            for (int r = 0; r < 4; ++r)
                hw[(rbase + r) * 68 + col] = acc[m][r];
        }
    }
    __syncthreads();

    // ---- softmax over K=10 + leaky relu, thread = (node, head) ----
    if (t < NPB * Hc) {   // 128 active
        const int h  = t & 15;
        const int ln = t >> 4;
        const float ar0 = a[0 * Hc + h];
        const float ar1 = a[1 * Hc + h];
        const float ar2 = a[2 * Hc + h];
        const float ar3 = a[3 * Hc + h];

        float4 hv[Kc];
        float  lg[Kc];
        float  mx = -1e30f;
#pragma unroll
        for (int k = 0; k < Kc; ++k) {
            hv[k] = *reinterpret_cast<const float4*>(hw + (ln * Kc + k) * 68 + h * 4);
            lg[k] = fmaf(hv[k].x, ar0, fmaf(hv[k].y, ar1, fmaf(hv[k].z, ar2, hv[k].w * ar3)));
            mx = fmaxf(mx, lg[k]);
        }
        float lsum = 0.f, o0 = 0.f, o1 = 0.f, o2 = 0.f, o3 = 0.f;
#pragma unroll
        for (int k = 0; k < Kc; ++k) {
            const float p = __expf(lg[k] - mx);
            lsum += p;
            o0 = fmaf(p, hv[k].x, o0);
            o1 = fmaf(p, hv[k].y, o1);
            o2 = fmaf(p, hv[k].z, o2);
            o3 = fmaf(p, hv[k].w, o3);
        }
        const float inv = 1.f / lsum;
        o0 *= inv; o1 *= inv; o2 *= inv; o3 *= inv;
        o0 = fmaxf(o0, 0.2f * o0);
        o1 = fmaxf(o1, 0.2f * o1);
        o2 = fmaxf(o2, 0.2f * o2);
        o3 = fmaxf(o3, 0.2f * o3);
        *reinterpret_cast<float4*>(ol + ln * 68 + h * 4) = make_float4(o0, o1, o2, o3);
    }
    __syncthreads();

    // ---- store transposed [B, 64, N], coalesced ----
    if (t < 128) {
        const int c  = t >> 1;   // channel 0..63
        const int nq = t & 1;    // node quad 0..1
        const int nb = blockIdx.x * NPB;
        const int b  = nb / Nc;
        const int n0 = nb - b * Nc;
        float4 v;
        v.x = ol[(nq * 4 + 0) * 68 + c];
        v.y = ol[(nq * 4 + 1) * 68 + c];
        v.z = ol[(nq * 4 + 2) * 68 + c];
        v.w = ol[(nq * 4 + 3) * 68 + c];
        *reinterpret_cast<float4*>(out + ((size_t)b * Cc + c) * Nc + n0 + nq * 4) = v;
    }
}

extern "C" void kernel_launch(void* const* d_in, const int* in_sizes, int n_in,
                              void* d_out, int out_size, void* d_ws, size_t ws_size,
                              hipStream_t stream) {
    const float* x = (const float*)d_in[0];
    const float* W = (const float*)d_in[1];
    const float* a = (const float*)d_in[2];
    float* out = (float*)d_out;
    unsigned short* wt = (unsigned short*)d_ws;   // 16 KB used

    prep_w<<<32, 256, 0, stream>>>(W, wt);
    gat_kernel<<<NODES / NPB, BLK, 0, stream>>>(x, wt, a, out);
}

// Round 5
// 235.942 us; speedup vs baseline: 2.0004x; 2.0004x over previous
//
#include <hip/hip_runtime.h>

typedef short bf16x8 __attribute__((ext_vector_type(8)));
typedef float f32x4 __attribute__((ext_vector_type(4)));

// Problem constants (fixed by reference setup_inputs)
constexpr int Bc = 4;
constexpr int Nc = 50000;
constexpr int Kc = 10;
constexpr int Fc = 128;
constexpr int Hc = 16;
constexpr int Cc = 64;            // 4*H output channels
constexpr int NODES = Bc * Nc;    // 200000
constexpr int NPB = 8;            // nodes per block
constexpr int ROWS = NPB * Kc;    // 80 GEMM rows per block
constexpr int MT = ROWS / 16;     // 5 M-tiles
constexpr int BLK = 256;          // 4 waves (N-split: wave w owns cols 16w..16w+15)

// LDS (phases alias):
//  phase A/B: xl bf16 [80 rows][256 B], XOR-swizzled        bytes [0, 20480)
//  phase C/D: hw f32 [80][68]  bytes [0, 21760) ; ol f32 [8][68] bytes [21760, 23936)
constexpr int LDS_BYTES = 23936;
constexpr int OL_OFF = 21760;

__device__ __forceinline__ unsigned short f2bf(float f) {
    // round-to-nearest-even fp32 -> bf16
    unsigned u = __builtin_bit_cast(unsigned, f);
    return (unsigned short)((u + 0x7fffu + ((u >> 16) & 1u)) >> 16);
}

// Prep: W [128][64] f32 -> per-lane B-fragment image in d_ws (bf16).
// dst = w*2048 + l*32 + kc*8 + j  <->  c = w*16 + (l&15), f = kc*32 + (l>>4)*8 + j.
__global__ __launch_bounds__(256)
void prep_w(const float* __restrict__ W, unsigned short* __restrict__ wt) {
    const int dst = blockIdx.x * 256 + threadIdx.x;   // 8192 total
    const int j  = dst & 7;
    const int kc = (dst >> 3) & 3;
    const int l  = (dst >> 5) & 63;
    const int w  = dst >> 11;
    const int c  = w * 16 + (l & 15);
    const int f  = kc * 32 + (l >> 4) * 8 + j;
    wt[dst] = f2bf(W[f * 64 + c]);
}

__global__ __launch_bounds__(BLK, 6)
void gat_kernel(const float* __restrict__ x,
                const unsigned short* __restrict__ wt_ws,
                const float* __restrict__ a,
                float* __restrict__ out)
{
    __shared__ __align__(16) char smem[LDS_BYTES];

    const int t  = threadIdx.x;
    const int w  = t >> 6;    // wave -> col-tile
    const int l  = t & 63;
    const int lr = l & 15;    // A-row / B-col within tile
    const int lk = l >> 4;    // k sub-block (8 contiguous k)

    // B fragments: 64 contiguous bytes per lane from the prepped image (L2-hit)
    bf16x8 bfrag[4];
    {
        const bf16x8* wp = reinterpret_cast<const bf16x8*>(wt_ws + w * 2048 + l * 32);
#pragma unroll
        for (int kc = 0; kc < 4; ++kc) bfrag[kc] = wp[kc];
    }

    // ---- phase A: stage x fp32 -> bf16 into LDS, swizzled; 32 B global / 16 B LDS per iter ----
    {
        const float* xg = x + (size_t)blockIdx.x * (ROWS * Fc);
#pragma unroll
        for (int i = 0; i < 5; ++i) {
            const int e0 = i * 2048 + t * 8;          // first f32 element of my 8
            const float4 v0 = *reinterpret_cast<const float4*>(xg + e0);
            const float4 v1 = *reinterpret_cast<const float4*>(xg + e0 + 4);
            const int row = i * 16 + (t >> 4);
            const int byt = ((t & 15) * 16) ^ ((row & 7) << 4);
            uint4 p;
            p.x = (unsigned)f2bf(v0.x) | ((unsigned)f2bf(v0.y) << 16);
            p.y = (unsigned)f2bf(v0.z) | ((unsigned)f2bf(v0.w) << 16);
            p.z = (unsigned)f2bf(v1.x) | ((unsigned)f2bf(v1.y) << 16);
            p.w = (unsigned)f2bf(v1.z) | ((unsigned)f2bf(v1.w) << 16);
            *reinterpret_cast<uint4*>(smem + row * 256 + byt) = p;
        }
    }
    __syncthreads();

    // ---- phase B: MFMA  hw[80][64] = x_bf16 . Wt^T ----
    f32x4 acc[MT];
#pragma unroll
    for (int m = 0; m < MT; ++m) acc[m] = (f32x4){0.f, 0.f, 0.f, 0.f};

#pragma unroll
    for (int m = 0; m < MT; ++m) {
        const int row = m * 16 + lr;
        const char* xrow = smem + row * 256;
        const int sw = (row & 7) << 4;
#pragma unroll
        for (int kc = 0; kc < 4; ++kc) {
            const bf16x8 af = *reinterpret_cast<const bf16x8*>(xrow + ((kc * 64 + lk * 16) ^ sw));
            acc[m] = __builtin_amdgcn_mfma_f32_16x16x32_bf16(af, bfrag[kc], acc[m], 0, 0, 0);
        }
    }
    __syncthreads();   // xl dead beyond this point (hw aliases it)

    // ---- phase C: acc -> hw LDS [80][68] f32 (D-frag: row = lk*4+r, col = lr) ----
    {
        float* hw = reinterpret_cast<float*>(smem);
        const int col = w * 16 + lr;
#pragma unroll
        for (int m = 0; m < MT; ++m) {
            const int rbase = m * 16 + lk * 4;
#pragma unroll
            for (int r = 0; r < 4; ++r)
                hw[(rbase + r) * 68 + col] = acc[m][r];
        }
    }
    __syncthreads();

    // ---- phase D: softmax over K=10 + leaky relu, thread = (node, head) ----
    const float* hw = reinterpret_cast<const float*>(smem);
    float* ol = reinterpret_cast<float*>(smem + OL_OFF);
    if (t < NPB * Hc) {   // 128 active
        const int h  = t & 15;
        const int ln = t >> 4;
        const float ar0 = a[0 * Hc + h];
        const float ar1 = a[1 * Hc + h];
        const float ar2 = a[2 * Hc + h];
        const float ar3 = a[3 * Hc + h];

        float4 hv[Kc];
        float  lg[Kc];
        float  mx = -1e30f;
#pragma unroll
        for (int k = 0; k < Kc; ++k) {
            hv[k] = *reinterpret_cast<const float4*>(hw + (ln * Kc + k) * 68 + h * 4);
            lg[k] = fmaf(hv[k].x, ar0, fmaf(hv[k].y, ar1, fmaf(hv[k].z, ar2, hv[k].w * ar3)));
            mx = fmaxf(mx, lg[k]);
        }
        float lsum = 0.f, o0 = 0.f, o1 = 0.f, o2 = 0.f, o3 = 0.f;
#pragma unroll
        for (int k = 0; k < Kc; ++k) {
            const float p = __expf(lg[k] - mx);
            lsum += p;
            o0 = fmaf(p, hv[k].x, o0);
            o1 = fmaf(p, hv[k].y, o1);
            o2 = fmaf(p, hv[k].z, o2);
            o3 = fmaf(p, hv[k].w, o3);
        }
        const float inv = 1.f / lsum;
        o0 *= inv; o1 *= inv; o2 *= inv; o3 *= inv;
        o0 = fmaxf(o0, 0.2f * o0);   // leaky_relu slope 0.2
        o1 = fmaxf(o1, 0.2f * o1);
        o2 = fmaxf(o2, 0.2f * o2);
        o3 = fmaxf(o3, 0.2f * o3);
        *reinterpret_cast<float4*>(ol + ln * 68 + h * 4) = make_float4(o0, o1, o2, o3);
    }
    __syncthreads();

    // ---- store transposed [B, 64, N], coalesced float4 ----
    if (t < 128) {
        const int c  = t >> 1;   // channel 0..63
        const int nq = t & 1;    // node quad 0..1
        const int nb = blockIdx.x * NPB;
        const int b  = nb / Nc;
        const int n0 = nb - b * Nc;
        float4 v;
        v.x = ol[(nq * 4 + 0) * 68 + c];
        v.y = ol[(nq * 4 + 1) * 68 + c];
        v.z = ol[(nq * 4 + 2) * 68 + c];
        v.w = ol[(nq * 4 + 3) * 68 + c];
        *reinterpret_cast<float4*>(out + ((size_t)b * Cc + c) * Nc + n0 + nq * 4) = v;
    }
}

extern "C" void kernel_launch(void* const* d_in, const int* in_sizes, int n_in,
                              void* d_out, int out_size, void* d_ws, size_t ws_size,
                              hipStream_t stream) {
    const float* x = (const float*)d_in[0];
    const float* W = (const float*)d_in[1];
    const float* a = (const float*)d_in[2];
    float* out = (float*)d_out;
    unsigned short* wt = (unsigned short*)d_ws;   // 16 KB used

    prep_w<<<32, 256, 0, stream>>>(W, wt);
    gat_kernel<<<NODES / NPB, BLK, 0, stream>>>(x, wt, a, out);
}